// Round 1
// baseline (402.427 us; speedup 1.0000x reference)
//
#include <hip/hip_runtime.h>
#include <hip/hip_bf16.h>
#include <stdint.h>
#include <math.h>

// Problem constants (fixed by reference)
#define NROWS   32768      // 8*4096
#define CDIM    768
#define NCODES  2048
#define NGROUPS 4          // col-groups for the argmin GEMM
#define COLS_PER_GROUP (NCODES / NGROUPS)   // 512
#define BM 128
#define BN 128
#define BK 32
#define CHUNKS (COLS_PER_GROUP / BN)        // 4

typedef __bf16 bf16;
typedef __attribute__((ext_vector_type(8))) __bf16 bf16x8;
typedef __attribute__((ext_vector_type(4))) float f32x4;

// ---------- helpers ----------
__device__ __forceinline__ unsigned short cvt_bf16(float f) {
    union { float f; unsigned int u; } v; v.f = f;
    unsigned int u = v.u;
    unsigned int r = (u + 0x7fffu + ((u >> 16) & 1u)) >> 16;   // RNE
    return (unsigned short)r;
}

__device__ __forceinline__ void async_load16(const void* gsrc, void* ldst) {
    __builtin_amdgcn_global_load_lds(
        (const __attribute__((address_space(1))) unsigned int*)gsrc,
        (__attribute__((address_space(3))) unsigned int*)ldst,
        16 /*bytes*/, 0 /*offset*/, 0 /*aux*/);
}

// ---------- 1) z fp32 -> bf16 ----------
__global__ __launch_bounds__(256) void convert_z(const float* __restrict__ z,
                                                 bf16* __restrict__ zb) {
    int i = blockIdx.x * 256 + threadIdx.x;       // 8 floats per thread, grid exact
    const float4* zp = (const float4*)z;
    float4 a = zp[2 * i];
    float4 b = zp[2 * i + 1];
    unsigned int w0 = (unsigned int)cvt_bf16(a.x) | ((unsigned int)cvt_bf16(a.y) << 16);
    unsigned int w1 = (unsigned int)cvt_bf16(a.z) | ((unsigned int)cvt_bf16(a.w) << 16);
    unsigned int w2 = (unsigned int)cvt_bf16(b.x) | ((unsigned int)cvt_bf16(b.y) << 16);
    unsigned int w3 = (unsigned int)cvt_bf16(b.z) | ((unsigned int)cvt_bf16(b.w) << 16);
    uint4 o; o.x = w0; o.y = w1; o.z = w2; o.w = w3;
    ((uint4*)zb)[i] = o;
}

// ---------- 2) embeddings -> bf16, ||e||^2, zero histogram ----------
__global__ __launch_bounds__(256) void prep_e(const float* __restrict__ e,
                                              bf16* __restrict__ eb,
                                              float* __restrict__ enorm,
                                              unsigned int* __restrict__ counts) {
    int k = blockIdx.x;        // one code per block
    int t = threadIdx.x;
    float s = 0.f;
    unsigned short* ebs = (unsigned short*)eb;
    #pragma unroll
    for (int c = 0; c < 3; ++c) {             // 768 = 3*256
        float v = e[(size_t)k * CDIM + c * 256 + t];
        s += v * v;
        ebs[(size_t)k * CDIM + c * 256 + t] = cvt_bf16(v);
    }
    // block reduce s
    #pragma unroll
    for (int o = 32; o > 0; o >>= 1) s += __shfl_down(s, o);
    __shared__ float red[4];
    if ((t & 63) == 0) red[t >> 6] = s;
    __syncthreads();
    if (t == 0) {
        enorm[k] = red[0] + red[1] + red[2] + red[3];
        counts[k] = 0u;
    }
}

// ---------- 3) bf16 MFMA GEMM with fused argmin ----------
// score[n][k] = ||e_k||^2 - 2 * dot(z_n, e_k); per-row argmin over this block's
// 512-column group; partial (val, idx) written per group.
__global__ __launch_bounds__(256) void gemm_argmin(const bf16* __restrict__ zb,
                                                   const bf16* __restrict__ eb,
                                                   const float* __restrict__ enorm,
                                                   float* __restrict__ bestv,
                                                   int* __restrict__ besti) {
    __shared__ __align__(16) bf16 As[BM * BK];
    __shared__ __align__(16) bf16 Bs[BN * BK];
    __shared__ float s_bv[2][BM];
    __shared__ int   s_bi[2][BM];

    const int tid  = threadIdx.x;
    const int m0   = blockIdx.x * BM;
    const int g    = blockIdx.y;
    const int cbase = g * COLS_PER_GROUP;

    const int lane = tid & 63;
    const int w    = tid >> 6;
    const int wy   = w >> 1;          // row 64-block of this wave
    const int wx   = w & 1;           // col 64-block of this wave
    const int quad = lane >> 4;       // 0..3
    const int l16  = lane & 15;

    if (tid < BM) {
        s_bv[0][tid] = 1e30f; s_bi[0][tid] = 0;
        s_bv[1][tid] = 1e30f; s_bi[1][tid] = 0;
    }

    for (int chunk = 0; chunk < CHUNKS; ++chunk) {
        const int c0 = cbase + chunk * BN;
        f32x4 acc[4][4] = {};

        for (int kt = 0; kt < CDIM; kt += BK) {
            __syncthreads();   // previous tile fully consumed / s_bv init visible
            // stage A and B tiles: slot s -> row s>>2, k-lane s&3 (8 bf16 = 16B each)
            #pragma unroll
            for (int t2 = 0; t2 < 2; ++t2) {
                int s   = t2 * 256 + tid;
                int row = s >> 2;
                int kl  = s & 3;
                async_load16(zb + (size_t)(m0 + row) * CDIM + kt + kl * 8, &As[s * 8]);
                async_load16(eb + (size_t)(c0 + row) * CDIM + kt + kl * 8, &Bs[s * 8]);
            }
            __syncthreads();   // barrier drains vmcnt -> LDS tiles complete

            bf16x8 af[4], bfr[4];
            #pragma unroll
            for (int i = 0; i < 4; ++i)
                af[i] = *(const bf16x8*)&As[(wy * 64 + i * 16 + l16) * BK + quad * 8];
            #pragma unroll
            for (int j = 0; j < 4; ++j)
                bfr[j] = *(const bf16x8*)&Bs[(wx * 64 + j * 16 + l16) * BK + quad * 8];
            #pragma unroll
            for (int i = 0; i < 4; ++i)
                #pragma unroll
                for (int j = 0; j < 4; ++j)
                    acc[i][j] = __builtin_amdgcn_mfma_f32_16x16x32_bf16(
                        af[i], bfr[j], acc[i][j], 0, 0, 0);
        }

        // epilogue: per-row argmin over this chunk's 64 cols handled by this wave
        float en[4]; int coln[4];
        #pragma unroll
        for (int j = 0; j < 4; ++j) {
            coln[j] = c0 + wx * 64 + j * 16 + l16;
            en[j]   = enorm[coln[j]];
        }
        #pragma unroll
        for (int i = 0; i < 4; ++i) {
            #pragma unroll
            for (int r = 0; r < 4; ++r) {
                float v = fmaf(-2.0f, acc[i][0][r], en[0]);
                int   idx = coln[0];
                #pragma unroll
                for (int j = 1; j < 4; ++j) {
                    float v2 = fmaf(-2.0f, acc[i][j][r], en[j]);
                    if (v2 < v) { v = v2; idx = coln[j]; }
                }
                // reduce across the 16 lanes holding different cols of this row
                #pragma unroll
                for (int msk = 1; msk < 16; msk <<= 1) {
                    float ov = __shfl_xor(v, msk);
                    int   oi = __shfl_xor(idx, msk);
                    if (ov < v || (ov == v && oi < idx)) { v = ov; idx = oi; }
                }
                if (l16 == 0) {
                    int row = wy * 64 + i * 16 + quad * 4 + r;
                    if (v < s_bv[wx][row]) { s_bv[wx][row] = v; s_bi[wx][row] = idx; }
                }
            }
        }
        // (each (wx,row) slot is owned by exactly one wave -> no race)
    }

    __syncthreads();
    if (tid < BM) {
        float v0 = s_bv[0][tid], v1 = s_bv[1][tid];
        int   i0 = s_bi[0][tid], i1 = s_bi[1][tid];
        float v; int ix;
        if (v1 < v0 || (v1 == v0 && i1 < i0)) { v = v1; ix = i1; }
        else                                   { v = v0; ix = i0; }
        bestv[(size_t)g * NROWS + m0 + tid] = v;
        besti[(size_t)g * NROWS + m0 + tid] = ix;
    }
}

// ---------- 4) combine groups, gather z_q, histogram ----------
__global__ __launch_bounds__(256) void gather_hist(const float* __restrict__ bestv,
                                                   const int* __restrict__ besti,
                                                   const float* __restrict__ e,
                                                   float* __restrict__ out,
                                                   unsigned int* __restrict__ counts) {
    int w    = threadIdx.x >> 6;
    int lane = threadIdx.x & 63;
    int n    = blockIdx.x * 4 + w;            // 8192 blocks * 4 waves = 32768 rows

    float v = bestv[n];
    int   idx = besti[n];
    #pragma unroll
    for (int g = 1; g < NGROUPS; ++g) {
        float v2 = bestv[(size_t)g * NROWS + n];
        int   i2 = besti[(size_t)g * NROWS + n];
        if (v2 < v || (v2 == v && i2 < idx)) { v = v2; idx = i2; }
    }
    if (lane == 0) atomicAdd(&counts[idx], 1u);

    const float4* src = (const float4*)(e + (size_t)idx * CDIM);
    float4*       dst = (float4*)(out + (size_t)n * CDIM);
    #pragma unroll
    for (int t = 0; t < 3; ++t)               // 192 float4 per row / 64 lanes
        dst[t * 64 + lane] = src[t * 64 + lane];
}

// ---------- 5) perplexity ----------
__global__ __launch_bounds__(256) void perplexity_k(const unsigned int* __restrict__ counts,
                                                    float* __restrict__ out) {
    int t = threadIdx.x;
    float s = 0.f;
    for (int k = t; k < NCODES; k += 256) {
        float p = (float)counts[k] * (1.0f / (float)NROWS);
        s += p * logf(p + 1e-10f);
    }
    #pragma unroll
    for (int o = 32; o > 0; o >>= 1) s += __shfl_down(s, o);
    __shared__ float red[4];
    if ((t & 63) == 0) red[t >> 6] = s;
    __syncthreads();
    if (t == 0) {
        float tot = red[0] + red[1] + red[2] + red[3];
        out[(size_t)NROWS * CDIM]     = 0.0f;        // vq_loss (eval mode)
        out[(size_t)NROWS * CDIM + 1] = expf(-tot);  // perplexity
    }
}

extern "C" void kernel_launch(void* const* d_in, const int* in_sizes, int n_in,
                              void* d_out, int out_size, void* d_ws, size_t ws_size,
                              hipStream_t stream) {
    const float* z = (const float*)d_in[0];   // [8,4096,768] fp32
    const float* e = (const float*)d_in[1];   // [2048,768]  fp32
    float* out = (float*)d_out;

    // workspace layout (all 16B aligned); total ~54.5 MB
    char* ws = (char*)d_ws;
    bf16* zb            = (bf16*)ws;           ws += (size_t)NROWS * CDIM * 2;      // 48 MB
    bf16* ebuf          = (bf16*)ws;           ws += (size_t)NCODES * CDIM * 2;     // 3 MB
    float* enorm        = (float*)ws;          ws += (size_t)NCODES * 4;            // 8 KB
    float* bestv        = (float*)ws;          ws += (size_t)NGROUPS * NROWS * 4;   // 512 KB
    int*   besti        = (int*)ws;            ws += (size_t)NGROUPS * NROWS * 4;   // 512 KB
    unsigned int* counts = (unsigned int*)ws;  ws += (size_t)NCODES * 4;            // 8 KB

    // 1) z -> bf16 (25165824 elems / 8 per thread / 256 per block = 12288 blocks)
    convert_z<<<12288, 256, 0, stream>>>(z, zb);
    // 2) embeddings -> bf16 + norms + zero hist
    prep_e<<<NCODES, 256, 0, stream>>>(e, ebuf, enorm, counts);
    // 3) fused GEMM + argmin
    dim3 gg(NROWS / BM, NGROUPS);             // 256 x 4
    gemm_argmin<<<gg, 256, 0, stream>>>(zb, ebuf, enorm, bestv, besti);
    // 4) combine + gather + histogram
    gather_hist<<<NROWS / 4, 256, 0, stream>>>(bestv, besti, e, out, counts);
    // 5) perplexity + vq_loss
    perplexity_k<<<1, 256, 0, stream>>>(counts, out);
}

// Round 2
// 345.580 us; speedup vs baseline: 1.1645x; 1.1645x over previous
//
#include <hip/hip_runtime.h>
#include <hip/hip_bf16.h>
#include <stdint.h>
#include <math.h>

// Problem constants (fixed by reference)
#define NROWS   32768      // 8*4096
#define CDIM    768
#define NCODES  2048
#define NGROUPS 4          // col-groups for the argmin GEMM
#define COLS_PER_GROUP (NCODES / NGROUPS)   // 512
#define BM 128
#define BN 128
#define BK 64
#define KTILES (CDIM / BK)                  // 12
#define CHUNKS (COLS_PER_GROUP / BN)        // 4

typedef __bf16 bf16;
typedef __attribute__((ext_vector_type(8))) __bf16 bf16x8;
typedef __attribute__((ext_vector_type(4))) float f32x4;

// ---------- helpers ----------
__device__ __forceinline__ unsigned short cvt_bf16(float f) {
    union { float f; unsigned int u; } v; v.f = f;
    unsigned int u = v.u;
    unsigned int r = (u + 0x7fffu + ((u >> 16) & 1u)) >> 16;   // RNE
    return (unsigned short)r;
}

__device__ __forceinline__ void async_load16(const void* gsrc, void* ldst) {
    __builtin_amdgcn_global_load_lds(
        (const __attribute__((address_space(1))) unsigned int*)gsrc,
        (__attribute__((address_space(3))) unsigned int*)ldst,
        16 /*bytes*/, 0 /*offset*/, 0 /*aux*/);
}

// ---------- 1) z fp32 -> bf16 ----------
__global__ __launch_bounds__(256) void convert_z(const float* __restrict__ z,
                                                 bf16* __restrict__ zb) {
    int i = blockIdx.x * 256 + threadIdx.x;       // 8 floats per thread, grid exact
    const float4* zp = (const float4*)z;
    float4 a = zp[2 * i];
    float4 b = zp[2 * i + 1];
    unsigned int w0 = (unsigned int)cvt_bf16(a.x) | ((unsigned int)cvt_bf16(a.y) << 16);
    unsigned int w1 = (unsigned int)cvt_bf16(a.z) | ((unsigned int)cvt_bf16(a.w) << 16);
    unsigned int w2 = (unsigned int)cvt_bf16(b.x) | ((unsigned int)cvt_bf16(b.y) << 16);
    unsigned int w3 = (unsigned int)cvt_bf16(b.z) | ((unsigned int)cvt_bf16(b.w) << 16);
    uint4 o; o.x = w0; o.y = w1; o.z = w2; o.w = w3;
    ((uint4*)zb)[i] = o;
}

// ---------- 2) embeddings -> bf16, ||e||^2, zero histogram ----------
__global__ __launch_bounds__(256) void prep_e(const float* __restrict__ e,
                                              bf16* __restrict__ eb,
                                              float* __restrict__ enorm,
                                              unsigned int* __restrict__ counts) {
    int k = blockIdx.x;        // one code per block
    int t = threadIdx.x;
    float s = 0.f;
    unsigned short* ebs = (unsigned short*)eb;
    #pragma unroll
    for (int c = 0; c < 3; ++c) {             // 768 = 3*256
        float v = e[(size_t)k * CDIM + c * 256 + t];
        s += v * v;
        ebs[(size_t)k * CDIM + c * 256 + t] = cvt_bf16(v);
    }
    #pragma unroll
    for (int o = 32; o > 0; o >>= 1) s += __shfl_down(s, o);
    __shared__ float red[4];
    if ((t & 63) == 0) red[t >> 6] = s;
    __syncthreads();
    if (t == 0) {
        enorm[k] = red[0] + red[1] + red[2] + red[3];
        counts[k] = 0u;
    }
}

// ---------- 3) bf16 MFMA GEMM with fused (deferred) argmin ----------
// score[n][k] = ||e_k||^2 - 2 * dot(z_n, e_k). Per-lane running argmin kept in
// VGPRs across all 4 chunks; single cross-lane reduction at block end.
// LDS layout XOR-swizzled: tile row r, 16B-chunk c stored at slot r*8+(c^(r&7)).
// We control both global_load_lds source mapping and the ds_read side, so the
// wave-uniform-dest constraint is satisfied and fragment reads hit all 32 banks.
__global__ __launch_bounds__(256, 3) void gemm_argmin(const bf16* __restrict__ zb,
                                                      const bf16* __restrict__ eb,
                                                      const float* __restrict__ enorm,
                                                      float* __restrict__ bestv,
                                                      int* __restrict__ besti) {
    __shared__ __align__(16) bf16 As[BM * BK];   // 16 KB
    __shared__ __align__(16) bf16 Bs[BN * BK];   // 16 KB
    __shared__ float s_bv[2][BM];
    __shared__ int   s_bi[2][BM];

    const int tid  = threadIdx.x;
    const int m0   = blockIdx.x * BM;
    const int g    = blockIdx.y;
    const int cbase = g * COLS_PER_GROUP;

    const int lane = tid & 63;
    const int w    = tid >> 6;
    const int wy   = w >> 1;          // row 64-block of this wave
    const int wx   = w & 1;           // col 64-block of this wave
    const int quad = lane >> 4;       // 0..3
    const int l16  = lane & 15;
    const int sw   = l16 & 7;         // swizzle phase for fragment reads

    float rv[16];
    int   ri[16];
    #pragma unroll
    for (int p = 0; p < 16; ++p) { rv[p] = 1e30f; ri[p] = 0; }

    for (int chunk = 0; chunk < CHUNKS; ++chunk) {
        const int c0 = cbase + chunk * BN;
        f32x4 acc[4][4] = {};

        for (int kt = 0; kt < CDIM; kt += BK) {
            __syncthreads();   // previous tile fully consumed
            // stage A and B tiles, swizzled: slot s holds (r=s>>3, c=(s&7)^(r&7))
            #pragma unroll
            for (int t2 = 0; t2 < 4; ++t2) {
                int s    = t2 * 256 + tid;          // 0..1023
                int r    = s >> 3;
                int csrc = (s & 7) ^ (r & 7);
                async_load16(zb + (size_t)(m0 + r) * CDIM + kt + csrc * 8, &As[s * 8]);
                async_load16(eb + (size_t)(c0 + r) * CDIM + kt + csrc * 8, &Bs[s * 8]);
            }
            __syncthreads();   // barrier drains vmcnt -> LDS tiles complete

            bf16x8 af[4], bfr[4];
            // k-step 0: c = quad
            #pragma unroll
            for (int i = 0; i < 4; ++i) {
                int r = wy * 64 + i * 16 + l16;
                af[i] = *(const bf16x8*)&As[(r * 8 + (quad ^ sw)) * 8];
            }
            #pragma unroll
            for (int j = 0; j < 4; ++j) {
                int r = wx * 64 + j * 16 + l16;
                bfr[j] = *(const bf16x8*)&Bs[(r * 8 + (quad ^ sw)) * 8];
            }
            #pragma unroll
            for (int i = 0; i < 4; ++i)
                #pragma unroll
                for (int j = 0; j < 4; ++j)
                    acc[i][j] = __builtin_amdgcn_mfma_f32_16x16x32_bf16(
                        af[i], bfr[j], acc[i][j], 0, 0, 0);
            // k-step 1: c = 4+quad = quad^4
            #pragma unroll
            for (int i = 0; i < 4; ++i) {
                int r = wy * 64 + i * 16 + l16;
                af[i] = *(const bf16x8*)&As[(r * 8 + ((quad ^ 4) ^ sw)) * 8];
            }
            #pragma unroll
            for (int j = 0; j < 4; ++j) {
                int r = wx * 64 + j * 16 + l16;
                bfr[j] = *(const bf16x8*)&Bs[(r * 8 + ((quad ^ 4) ^ sw)) * 8];
            }
            #pragma unroll
            for (int i = 0; i < 4; ++i)
                #pragma unroll
                for (int j = 0; j < 4; ++j)
                    acc[i][j] = __builtin_amdgcn_mfma_f32_16x16x32_bf16(
                        af[i], bfr[j], acc[i][j], 0, 0, 0);
        }

        // cheap per-chunk epilogue: per-lane select only, no shuffles
        float en[4];
        #pragma unroll
        for (int j = 0; j < 4; ++j) en[j] = enorm[c0 + wx * 64 + j * 16 + l16];
        const int colbase = c0 + wx * 64 + l16;
        #pragma unroll
        for (int i = 0; i < 4; ++i) {
            #pragma unroll
            for (int r = 0; r < 4; ++r) {
                float v   = fmaf(-2.0f, acc[i][0][r], en[0]);
                int   idx = colbase;
                #pragma unroll
                for (int j = 1; j < 4; ++j) {
                    float v2 = fmaf(-2.0f, acc[i][j][r], en[j]);
                    int   i2 = colbase + j * 16;
                    if (v2 < v) { v = v2; idx = i2; }
                }
                int p = i * 4 + r;
                if (v < rv[p]) { rv[p] = v; ri[p] = idx; }
            }
        }
    }

    // single cross-lane argmin reduction (over the 16 l16 lanes per quad-row)
    #pragma unroll
    for (int p = 0; p < 16; ++p) {
        float v = rv[p]; int idx = ri[p];
        #pragma unroll
        for (int msk = 1; msk < 16; msk <<= 1) {
            float ov = __shfl_xor(v, msk);
            int   oi = __shfl_xor(idx, msk);
            if (ov < v || (ov == v && oi < idx)) { v = ov; idx = oi; }
        }
        if (l16 == 0) {
            int row = wy * 64 + (p >> 2) * 16 + quad * 4 + (p & 3);
            s_bv[wx][row] = v; s_bi[wx][row] = idx;
        }
    }

    __syncthreads();
    if (tid < BM) {
        float v0 = s_bv[0][tid], v1 = s_bv[1][tid];
        int   i0 = s_bi[0][tid], i1 = s_bi[1][tid];
        float v; int ix;
        if (v1 < v0 || (v1 == v0 && i1 < i0)) { v = v1; ix = i1; }
        else                                   { v = v0; ix = i0; }
        bestv[(size_t)g * NROWS + m0 + tid] = v;
        besti[(size_t)g * NROWS + m0 + tid] = ix;
    }
}

// ---------- 4) combine groups, gather z_q, histogram ----------
__global__ __launch_bounds__(256) void gather_hist(const float* __restrict__ bestv,
                                                   const int* __restrict__ besti,
                                                   const float* __restrict__ e,
                                                   float* __restrict__ out,
                                                   unsigned int* __restrict__ counts) {
    int w    = threadIdx.x >> 6;
    int lane = threadIdx.x & 63;
    int n    = blockIdx.x * 4 + w;            // 8192 blocks * 4 waves = 32768 rows

    float v = bestv[n];
    int   idx = besti[n];
    #pragma unroll
    for (int g = 1; g < NGROUPS; ++g) {
        float v2 = bestv[(size_t)g * NROWS + n];
        int   i2 = besti[(size_t)g * NROWS + n];
        if (v2 < v || (v2 == v && i2 < idx)) { v = v2; idx = i2; }
    }
    if (lane == 0) atomicAdd(&counts[idx], 1u);

    const float4* src = (const float4*)(e + (size_t)idx * CDIM);
    float4*       dst = (float4*)(out + (size_t)n * CDIM);
    #pragma unroll
    for (int t = 0; t < 3; ++t)               // 192 float4 per row / 64 lanes
        dst[t * 64 + lane] = src[t * 64 + lane];
}

// ---------- 5) perplexity ----------
__global__ __launch_bounds__(256) void perplexity_k(const unsigned int* __restrict__ counts,
                                                    float* __restrict__ out) {
    int t = threadIdx.x;
    float s = 0.f;
    for (int k = t; k < NCODES; k += 256) {
        float p = (float)counts[k] * (1.0f / (float)NROWS);
        s += p * logf(p + 1e-10f);
    }
    #pragma unroll
    for (int o = 32; o > 0; o >>= 1) s += __shfl_down(s, o);
    __shared__ float red[4];
    if ((t & 63) == 0) red[t >> 6] = s;
    __syncthreads();
    if (t == 0) {
        float tot = red[0] + red[1] + red[2] + red[3];
        out[(size_t)NROWS * CDIM]     = 0.0f;        // vq_loss (eval mode)
        out[(size_t)NROWS * CDIM + 1] = expf(-tot);  // perplexity
    }
}

extern "C" void kernel_launch(void* const* d_in, const int* in_sizes, int n_in,
                              void* d_out, int out_size, void* d_ws, size_t ws_size,
                              hipStream_t stream) {
    const float* z = (const float*)d_in[0];   // [8,4096,768] fp32
    const float* e = (const float*)d_in[1];   // [2048,768]  fp32
    float* out = (float*)d_out;

    // workspace layout (all 16B aligned); total ~54.5 MB
    char* ws = (char*)d_ws;
    bf16* zb            = (bf16*)ws;           ws += (size_t)NROWS * CDIM * 2;      // 48 MB
    bf16* ebuf          = (bf16*)ws;           ws += (size_t)NCODES * CDIM * 2;     // 3 MB
    float* enorm        = (float*)ws;          ws += (size_t)NCODES * 4;            // 8 KB
    float* bestv        = (float*)ws;          ws += (size_t)NGROUPS * NROWS * 4;   // 512 KB
    int*   besti        = (int*)ws;            ws += (size_t)NGROUPS * NROWS * 4;   // 512 KB
    unsigned int* counts = (unsigned int*)ws;  ws += (size_t)NCODES * 4;            // 8 KB

    convert_z<<<12288, 256, 0, stream>>>(z, zb);
    prep_e<<<NCODES, 256, 0, stream>>>(e, ebuf, enorm, counts);
    dim3 gg(NROWS / BM, NGROUPS);             // 256 x 4
    gemm_argmin<<<gg, 256, 0, stream>>>(zb, ebuf, enorm, bestv, besti);
    gather_hist<<<NROWS / 4, 256, 0, stream>>>(bestv, besti, e, out, counts);
    perplexity_k<<<1, 256, 0, stream>>>(counts, out);
}

// Round 3
// 340.870 us; speedup vs baseline: 1.1806x; 1.0138x over previous
//
#include <hip/hip_runtime.h>
#include <hip/hip_bf16.h>
#include <stdint.h>
#include <math.h>

// Problem constants (fixed by reference)
#define NROWS   32768      // 8*4096
#define CDIM    768
#define NCODES  2048
#define NGROUPS 4          // col-groups for the argmin GEMM
#define COLS_PER_GROUP (NCODES / NGROUPS)   // 512
#define BM 128
#define BN 128
#define BK 64
#define CHUNKS (COLS_PER_GROUP / BN)        // 4
#define ESCALE 2048.0f                      // 2^11: lifts e into e4m3 range
#define INV2ESCALE (2.0f / ESCALE)          // folds the "-2 * dot" back

typedef __attribute__((ext_vector_type(4))) float f32x4;

// ---------- helpers ----------
__device__ __forceinline__ void async_load16(const void* gsrc, void* ldst) {
    __builtin_amdgcn_global_load_lds(
        (const __attribute__((address_space(1))) unsigned int*)gsrc,
        (__attribute__((address_space(3))) unsigned int*)ldst,
        16 /*bytes*/, 0 /*offset*/, 0 /*aux*/);
}

__device__ __forceinline__ unsigned int pack4_fp8(float x, float y, float z, float w) {
    int v = __builtin_amdgcn_cvt_pk_fp8_f32(x, y, 0, false);   // bytes 0,1
    v     = __builtin_amdgcn_cvt_pk_fp8_f32(z, w, v, true);    // bytes 2,3
    return (unsigned int)v;
}

// ---------- 1) fused: z -> fp8  AND  e -> fp8*2048 + ||e||^2 + zero hist ----------
#define ZBLOCKS 6144       // 25165824 elems / (256 thr * 16 elem)
__global__ __launch_bounds__(256) void convert_fused(const float* __restrict__ z,
                                                     const float* __restrict__ e,
                                                     unsigned char* __restrict__ z8,
                                                     unsigned char* __restrict__ e8,
                                                     float* __restrict__ enorm,
                                                     unsigned int* __restrict__ counts) {
    int b = blockIdx.x;
    if (b < ZBLOCKS) {
        int i = b * 256 + threadIdx.x;            // 16 floats per thread, grid exact
        const float4* zp = (const float4*)z;
        float4 a0 = zp[4 * i + 0];
        float4 a1 = zp[4 * i + 1];
        float4 a2 = zp[4 * i + 2];
        float4 a3 = zp[4 * i + 3];
        uint4 o;
        o.x = pack4_fp8(a0.x, a0.y, a0.z, a0.w);
        o.y = pack4_fp8(a1.x, a1.y, a1.z, a1.w);
        o.z = pack4_fp8(a2.x, a2.y, a2.z, a2.w);
        o.w = pack4_fp8(a3.x, a3.y, a3.z, a3.w);
        ((uint4*)z8)[i] = o;
    } else {
        int k = b - ZBLOCKS;                      // one code per block
        int t = threadIdx.x;
        float s = 0.f;
        if (t < 192) {                            // 192 * 4 = 768 elems
            float4 v = ((const float4*)(e + (size_t)k * CDIM))[t];
            s = v.x * v.x + v.y * v.y + v.z * v.z + v.w * v.w;
            ((unsigned int*)(e8 + (size_t)k * CDIM))[t] =
                pack4_fp8(v.x * ESCALE, v.y * ESCALE, v.z * ESCALE, v.w * ESCALE);
        }
        #pragma unroll
        for (int o = 32; o > 0; o >>= 1) s += __shfl_down(s, o);
        __shared__ float red[4];
        if ((t & 63) == 0) red[t >> 6] = s;
        __syncthreads();
        if (t == 0) {
            enorm[k] = red[0] + red[1] + red[2] + red[3];
            counts[k] = 0u;
        }
    }
}

// ---------- 2) fp8 MFMA GEMM with fused (deferred) argmin ----------
// dotE[n][k] = sum q8(z_n) * q8(2048*e_k); score = ||e_k||^2 - (2/2048)*dotE.
// LDS: rows of 64 B (BK=64 fp8), 16-B granule g of row r stored at slot g^(r&3)
// (global_load_lds dest must be contiguous lane*16, so swizzle is granule-level).
// Fragment (16x16x32 fp8, shape-identical mapping to verified bf16 16x16x32):
// lane holds A[m=lane&15][k=step*32 + quad*8 + j], j=0..7 -> one b64 per step.
__global__ __launch_bounds__(256, 3) void gemm_argmin(const unsigned char* __restrict__ z8,
                                                      const unsigned char* __restrict__ e8,
                                                      const float* __restrict__ enorm,
                                                      float* __restrict__ bestv,
                                                      int* __restrict__ besti) {
    __shared__ __align__(16) unsigned char As[BM * BK];   // 8 KB
    __shared__ __align__(16) unsigned char Bs[BN * BK];   // 8 KB
    __shared__ float s_bv[2][BM];
    __shared__ int   s_bi[2][BM];

    const int tid  = threadIdx.x;
    const int m0   = blockIdx.x * BM;
    const int g    = blockIdx.y;
    const int cbase = g * COLS_PER_GROUP;

    const int lane = tid & 63;
    const int w    = tid >> 6;
    const int wy   = w >> 1;          // row 64-block of this wave
    const int wx   = w & 1;           // col 64-block of this wave
    const int quad = lane >> 4;       // 0..3
    const int l16  = lane & 15;
    const int goff = (quad & 1) * 8;  // byte offset within a 16-B granule
    const int ghi  = quad >> 1;       // granule half selected by quad

    float rv[16];
    int   ri[16];
    #pragma unroll
    for (int p = 0; p < 16; ++p) { rv[p] = 1e30f; ri[p] = 0; }

    for (int chunk = 0; chunk < CHUNKS; ++chunk) {
        const int c0 = cbase + chunk * BN;
        f32x4 acc[4][4] = {};

        for (int kt = 0; kt < CDIM; kt += BK) {
            __syncthreads();   // previous tile fully consumed
            // stage A/B: 512 granules each; slot s holds global granule (s&3)^(r&3)
            #pragma unroll
            for (int t2 = 0; t2 < 2; ++t2) {
                int s    = t2 * 256 + tid;          // 0..511
                int r    = s >> 2;
                int gsrc = (s & 3) ^ (r & 3);
                async_load16(z8 + (size_t)(m0 + r) * CDIM + kt + gsrc * 16, &As[s * 16]);
                async_load16(e8 + (size_t)(c0 + r) * CDIM + kt + gsrc * 16, &Bs[s * 16]);
            }
            __syncthreads();   // barrier drains vmcnt -> LDS tiles complete

            #pragma unroll
            for (int step = 0; step < 2; ++step) {
                const int g0 = step * 2 + ghi;      // global granule wanted
                long af[4], bfr[4];
                #pragma unroll
                for (int i = 0; i < 4; ++i) {
                    int r = wy * 64 + i * 16 + l16;
                    af[i] = *(const long*)&As[r * BK + ((g0 ^ (r & 3)) * 16) + goff];
                }
                #pragma unroll
                for (int j = 0; j < 4; ++j) {
                    int r = wx * 64 + j * 16 + l16;
                    bfr[j] = *(const long*)&Bs[r * BK + ((g0 ^ (r & 3)) * 16) + goff];
                }
                #pragma unroll
                for (int i = 0; i < 4; ++i)
                    #pragma unroll
                    for (int j = 0; j < 4; ++j)
                        acc[i][j] = __builtin_amdgcn_mfma_f32_16x16x32_fp8_fp8(
                            af[i], bfr[j], acc[i][j], 0, 0, 0);
            }
        }

        // cheap per-chunk epilogue: per-lane select only, no shuffles
        float en[4];
        #pragma unroll
        for (int j = 0; j < 4; ++j) en[j] = enorm[c0 + wx * 64 + j * 16 + l16];
        const int colbase = c0 + wx * 64 + l16;
        #pragma unroll
        for (int i = 0; i < 4; ++i) {
            #pragma unroll
            for (int r = 0; r < 4; ++r) {
                float v   = fmaf(-INV2ESCALE, acc[i][0][r], en[0]);
                int   idx = colbase;
                #pragma unroll
                for (int j = 1; j < 4; ++j) {
                    float v2 = fmaf(-INV2ESCALE, acc[i][j][r], en[j]);
                    int   i2 = colbase + j * 16;
                    if (v2 < v) { v = v2; idx = i2; }
                }
                int p = i * 4 + r;
                if (v < rv[p]) { rv[p] = v; ri[p] = idx; }
            }
        }
    }

    // single cross-lane argmin reduction (over the 16 l16 lanes per quad-row)
    #pragma unroll
    for (int p = 0; p < 16; ++p) {
        float v = rv[p]; int idx = ri[p];
        #pragma unroll
        for (int msk = 1; msk < 16; msk <<= 1) {
            float ov = __shfl_xor(v, msk);
            int   oi = __shfl_xor(idx, msk);
            if (ov < v || (ov == v && oi < idx)) { v = ov; idx = oi; }
        }
        if (l16 == 0) {
            int row = wy * 64 + (p >> 2) * 16 + quad * 4 + (p & 3);
            s_bv[wx][row] = v; s_bi[wx][row] = idx;
        }
    }

    __syncthreads();
    if (tid < BM) {
        float v0 = s_bv[0][tid], v1 = s_bv[1][tid];
        int   i0 = s_bi[0][tid], i1 = s_bi[1][tid];
        float v; int ix;
        if (v1 < v0 || (v1 == v0 && i1 < i0)) { v = v1; ix = i1; }
        else                                   { v = v0; ix = i0; }
        bestv[(size_t)g * NROWS + m0 + tid] = v;
        besti[(size_t)g * NROWS + m0 + tid] = ix;
    }
}

// ---------- 3) combine groups, gather z_q, histogram ----------
__global__ __launch_bounds__(256) void gather_hist(const float* __restrict__ bestv,
                                                   const int* __restrict__ besti,
                                                   const float* __restrict__ e,
                                                   float* __restrict__ out,
                                                   unsigned int* __restrict__ counts) {
    int w    = threadIdx.x >> 6;
    int lane = threadIdx.x & 63;
    int n    = blockIdx.x * 4 + w;            // 8192 blocks * 4 waves = 32768 rows

    float v = bestv[n];
    int   idx = besti[n];
    #pragma unroll
    for (int g = 1; g < NGROUPS; ++g) {
        float v2 = bestv[(size_t)g * NROWS + n];
        int   i2 = besti[(size_t)g * NROWS + n];
        if (v2 < v || (v2 == v && i2 < idx)) { v = v2; idx = i2; }
    }
    if (lane == 0) atomicAdd(&counts[idx], 1u);

    const float4* src = (const float4*)(e + (size_t)idx * CDIM);
    float4*       dst = (float4*)(out + (size_t)n * CDIM);
    #pragma unroll
    for (int t = 0; t < 3; ++t)               // 192 float4 per row / 64 lanes
        dst[t * 64 + lane] = src[t * 64 + lane];
}

// ---------- 4) perplexity ----------
__global__ __launch_bounds__(256) void perplexity_k(const unsigned int* __restrict__ counts,
                                                    float* __restrict__ out) {
    int t = threadIdx.x;
    float s = 0.f;
    for (int k = t; k < NCODES; k += 256) {
        float p = (float)counts[k] * (1.0f / (float)NROWS);
        s += p * logf(p + 1e-10f);
    }
    #pragma unroll
    for (int o = 32; o > 0; o >>= 1) s += __shfl_down(s, o);
    __shared__ float red[4];
    if ((t & 63) == 0) red[t >> 6] = s;
    __syncthreads();
    if (t == 0) {
        float tot = red[0] + red[1] + red[2] + red[3];
        out[(size_t)NROWS * CDIM]     = 0.0f;        // vq_loss (eval mode)
        out[(size_t)NROWS * CDIM + 1] = expf(-tot);  // perplexity
    }
}

extern "C" void kernel_launch(void* const* d_in, const int* in_sizes, int n_in,
                              void* d_out, int out_size, void* d_ws, size_t ws_size,
                              hipStream_t stream) {
    const float* z = (const float*)d_in[0];   // [8,4096,768] fp32
    const float* e = (const float*)d_in[1];   // [2048,768]  fp32
    float* out = (float*)d_out;

    // workspace layout (all 16B aligned); total ~27 MB
    char* ws = (char*)d_ws;
    unsigned char* z8   = (unsigned char*)ws;  ws += (size_t)NROWS * CDIM;          // 24 MB
    unsigned char* e8   = (unsigned char*)ws;  ws += (size_t)NCODES * CDIM;         // 1.5 MB
    float* enorm        = (float*)ws;          ws += (size_t)NCODES * 4;            // 8 KB
    float* bestv        = (float*)ws;          ws += (size_t)NGROUPS * NROWS * 4;   // 512 KB
    int*   besti        = (int*)ws;            ws += (size_t)NGROUPS * NROWS * 4;   // 512 KB
    unsigned int* counts = (unsigned int*)ws;  ws += (size_t)NCODES * 4;            // 8 KB

    convert_fused<<<ZBLOCKS + NCODES, 256, 0, stream>>>(z, e, z8, e8, enorm, counts);
    dim3 gg(NROWS / BM, NGROUPS);             // 256 x 4
    gemm_argmin<<<gg, 256, 0, stream>>>(z8, e8, enorm, bestv, besti);
    gather_hist<<<NROWS / 4, 256, 0, stream>>>(bestv, besti, e, out, counts);
    perplexity_k<<<1, 256, 0, stream>>>(counts, out);
}